// Round 4
// baseline (191.861 us; speedup 1.0000x reference)
//
#include <hip/hip_runtime.h>
#include <math.h>

#define NB 64
#define HH 512
#define WW 512
#define KK 31
#define PP 15
#define TS 32                 // output rows per strip
#define NSTRIP (HH / TS)      // 16 strips per image
#define HR (TS + KK - 1)      // 62 H rows held in LDS
#define NPAIR (HR / 2)        // 31 row pairs in phase 1

typedef _Float16 f16;
typedef f16 f16x8 __attribute__((ext_vector_type(8)));
typedef f16 f16x4 __attribute__((ext_vector_type(4)));
typedef f16 f16x2 __attribute__((ext_vector_type(2)));

__device__ __forceinline__ f16x2 shfl_up2(f16x2 v, int delta) {
    int x = __shfl_up(__builtin_bit_cast(int, v), delta);
    return __builtin_bit_cast(f16x2, x);
}
__device__ __forceinline__ f16x2 shfl_dn2(f16x2 v, int delta) {
    int x = __shfl_down(__builtin_bit_cast(int, v), delta);
    return __builtin_bit_cast(f16x2, x);
}
__device__ __forceinline__ f16x2 sel2(bool c, f16x2 v) {
    f16x2 z = {(f16)0, (f16)0};
    return c ? v : z;
}
// anchor: force a float4 to be materialized in VGPRs at this program point
__device__ __forceinline__ void keep4(float4& v) {
    asm volatile("" : "+v"(v.x), "+v"(v.y), "+v"(v.z), "+v"(v.w));
}

// ws layout: part[0..1023] = per-block inter, part[1024..2047] = per-block union

__global__ __launch_bounds__(512, 4) void dice_fused_kernel(
        const float* __restrict__ pred,
        const float* __restrict__ mask,
        float* __restrict__ part) {
    const int strip = blockIdx.x;
    const int b     = blockIdx.y;
    const int t     = threadIdx.x;
    const int wave  = t >> 6;
    const int lane  = t & 63;

    __shared__ f16 Hs[HR][WW];    // 62 x 512 fp16 = 63.5 KB : horizontal box sums
    __shared__ float red[16];     // total ~63.6 KB -> 2 blocks/CU

    const float* mb = mask + (size_t)b * HH * WW;
    const float* pb = pred + (size_t)b * HH * WW;
    const int y0 = strip * TS;

    // phase-2 coordinates (needed early for the prefetch)
    const int q  = t & 127;
    const int g  = t >> 7;               // 0..3
    const int c  = q * 4;
    const int r0 = g * 8;                // first output row (strip-relative)

    // ============ Phase 1 global loads (issued first) ==============================
    const int xbase = lane * 8;
    float va[4][8], vb[4][8];
    #pragma unroll
    for (int k = 0; k < 4; ++k) {
        const int p = k * 8 + wave;          // pair index 0..31 (31 invalid)
        const int gya = y0 + 2 * p - PP;
        const int gyb = gya + 1;
        const bool pa = (p < NPAIR) && (gya >= 0) && (gya < HH);
        const bool qb = (p < NPAIR) && (gyb >= 0) && (gyb < HH);
        if (pa) {
            const float* row = mb + (size_t)gya * WW + xbase;
            const float4 u = *(const float4*)(row);
            const float4 v = *(const float4*)(row + 4);
            va[k][0] = u.x; va[k][1] = u.y; va[k][2] = u.z; va[k][3] = u.w;
            va[k][4] = v.x; va[k][5] = v.y; va[k][6] = v.z; va[k][7] = v.w;
        } else {
            #pragma unroll
            for (int j = 0; j < 8; ++j) va[k][j] = 0.0f;
        }
        if (qb) {
            const float* row = mb + (size_t)gyb * WW + xbase;
            const float4 u = *(const float4*)(row);
            const float4 v = *(const float4*)(row + 4);
            vb[k][0] = u.x; vb[k][1] = u.y; vb[k][2] = u.z; vb[k][3] = u.w;
            vb[k][4] = v.x; vb[k][5] = v.y; vb[k][6] = v.z; vb[k][7] = v.w;
        } else {
            #pragma unroll
            for (int j = 0; j < 8; ++j) vb[k][j] = 0.0f;
        }
    }

    // ============ Phase-2 global prefetch, anchored so it can't be sunk ============
    // Latency hides under phase-1 compute; data is ready right after the barrier.
    float4 M[8], Pq[8];
    #pragma unroll
    for (int i = 0; i < 8; ++i) {
        const int y = y0 + r0 + i;
        M[i]  = *(const float4*)(mb + (size_t)y * WW + c);
        Pq[i] = *(const float4*)(pb + (size_t)y * WW + c);
    }
    #pragma unroll
    for (int i = 0; i < 8; ++i) { keep4(M[i]); keep4(Pq[i]); }

    // ============ Phase 1 compute: local-tap horizontal 31-sum, 2 rows packed ======
    const bool lm1 = (lane >= 1);
    const bool lm2 = (lane >= 2);
    const bool lp1 = (lane <= 62);
    const bool lp2 = (lane <= 61);

    #pragma unroll
    for (int k = 0; k < 4; ++k) {
        const int p = k * 8 + wave;
        if (p >= NPAIR) continue;            // only wave 7, k=3 drops out
        const int ra = 2 * p;
        const int rb = ra + 1;

        float sa[8], sb[8];
        sa[0] = va[k][0]; sb[0] = vb[k][0];
        #pragma unroll
        for (int j = 1; j < 8; ++j) { sa[j] = sa[j-1] + va[k][j]; sb[j] = sb[j-1] + vb[k][j]; }

        f16x2 ps[8];
        #pragma unroll
        for (int j = 0; j < 8; ++j)
            ps[j] = __builtin_bit_cast(f16x2, __builtin_amdgcn_cvt_pkrtz(sa[j], sb[j]));
        const f16x2 pT = ps[7];

        f16x2 A[7];
        #pragma unroll
        for (int j = 0; j < 7; ++j) A[j] = shfl_up2(pT - ps[j], 2);
        const f16x2 Bprev = shfl_up2(pT, 1);
        const f16x2 Cfull = shfl_dn2(pT, 1);
        f16x2 Cp[7];
        #pragma unroll
        for (int j = 0; j < 7; ++j) Cp[j] = shfl_dn2(ps[j], 2);

        f16x2 base = pT;
        base += sel2(lm1, Bprev);
        base += sel2(lp1, Cfull);

        f16x8 ha, hb;
        #pragma unroll
        for (int j = 0; j < 8; ++j) {
            f16x2 acc = base;
            if (j < 7) acc += sel2(lm2, A[j]);
            if (j > 0) acc += sel2(lp2, Cp[j-1]);
            ha[j] = acc[0];
            hb[j] = acc[1];
        }
        *(f16x8*)&Hs[ra][xbase] = ha;
        *(f16x8*)&Hs[rb][xbase] = hb;
    }
    __syncthreads();

    // ================= Phase 2: vertical running 31-sum + fused epilogue ===========
    // Warm-up in packed fp16 (v_pk_add_f16), two 15-row partial sums for accuracy.
    // hl rows (r0..r0+7) are saved during warm-up instead of re-read; he rows
    // pre-read before the loop -> inner loop is pure register math.
    f16x4 hl8[8], he8[8];
    f16x4 accA = {(f16)0, (f16)0, (f16)0, (f16)0};
    f16x4 accB = {(f16)0, (f16)0, (f16)0, (f16)0};
    #pragma unroll
    for (int j = 0; j < 8; ++j) {            // rows r0..r0+7: save + accumulate
        hl8[j] = *(const f16x4*)&Hs[r0 + j][c];
        accA += hl8[j];
    }
    #pragma unroll
    for (int j = 8; j < 15; ++j) accA += *(const f16x4*)&Hs[r0 + j][c];
    #pragma unroll
    for (int j = 15; j < 30; ++j) accB += *(const f16x4*)&Hs[r0 + j][c];
    #pragma unroll
    for (int i = 0; i < 8; ++i) he8[i] = *(const f16x4*)&Hs[r0 + 30 + i][c];

    float4 B;
    B.x = (float)accA[0] + (float)accB[0];
    B.y = (float)accA[1] + (float)accB[1];
    B.z = (float)accA[2] + (float)accB[2];
    B.w = (float)accA[3] + (float)accB[3];

    float4 I4 = make_float4(0.f, 0.f, 0.f, 0.f);
    float4 U4 = make_float4(0.f, 0.f, 0.f, 0.f);
    const float inv2 = 1.0f / (float)(KK * KK);

    #pragma unroll
    for (int i = 0; i < 8; ++i) {
        const f16x4 he = he8[i];
        const f16x4 hl = hl8[i];
        const float4 m4 = M[i];
        const float4 p4 = Pq[i];

        B.x += (float)he[0]; B.y += (float)he[1]; B.z += (float)he[2]; B.w += (float)he[3];

        const float w0 = fmaf(5.0f, fabsf(fmaf(B.x, inv2, -m4.x)), 1.0f);
        const float w1 = fmaf(5.0f, fabsf(fmaf(B.y, inv2, -m4.y)), 1.0f);
        const float w2 = fmaf(5.0f, fabsf(fmaf(B.z, inv2, -m4.z)), 1.0f);
        const float w3 = fmaf(5.0f, fabsf(fmaf(B.w, inv2, -m4.w)), 1.0f);
        const float sg0 = __builtin_amdgcn_rcpf(1.0f + __expf(-p4.x));
        const float sg1 = __builtin_amdgcn_rcpf(1.0f + __expf(-p4.y));
        const float sg2 = __builtin_amdgcn_rcpf(1.0f + __expf(-p4.z));
        const float sg3 = __builtin_amdgcn_rcpf(1.0f + __expf(-p4.w));

        I4.x = fmaf(sg0 * m4.x, w0, I4.x);  U4.x = fmaf(sg0 + m4.x, w0, U4.x);
        I4.y = fmaf(sg1 * m4.y, w1, I4.y);  U4.y = fmaf(sg1 + m4.y, w1, U4.y);
        I4.z = fmaf(sg2 * m4.z, w2, I4.z);  U4.z = fmaf(sg2 + m4.z, w2, U4.z);
        I4.w = fmaf(sg3 * m4.w, w3, I4.w);  U4.w = fmaf(sg3 + m4.w, w3, U4.w);

        B.x -= (float)hl[0]; B.y -= (float)hl[1]; B.z -= (float)hl[2]; B.w -= (float)hl[3];
    }

    // ================= Block reduction -> per-block partials ======================
    float inter = I4.x + I4.y + I4.z + I4.w;
    float uni   = U4.x + U4.y + U4.z + U4.w;
    #pragma unroll
    for (int off = 32; off > 0; off >>= 1) {
        inter += __shfl_down(inter, off);
        uni   += __shfl_down(uni, off);
    }
    if (lane == 0) { red[wave] = inter; red[8 + wave] = uni; }
    __syncthreads();
    if (t == 0) {
        float ti = 0.f, tu = 0.f;
        #pragma unroll
        for (int w2 = 0; w2 < 8; ++w2) { ti += red[w2]; tu += red[8 + w2]; }
        const int bid = b * NSTRIP + strip;
        part[bid] = ti;
        part[NB * NSTRIP + bid] = tu;
    }
}

// ---------------- Final reduction ---------------
__global__ void dice_final_kernel(const float* __restrict__ part,
                                  float* __restrict__ out) {
    const int t = threadIdx.x;  // 64 threads, one per image
    float inter = 0.0f, uni = 0.0f;
    #pragma unroll
    for (int s = 0; s < NSTRIP; ++s) {
        inter += part[t * NSTRIP + s];
        uni   += part[NB * NSTRIP + t * NSTRIP + s];
    }
    float wd = 1.0f - (2.0f * inter + 0.5f) / (uni + 0.5f);
    #pragma unroll
    for (int off = 32; off > 0; off >>= 1) wd += __shfl_down(wd, off);
    if (t == 0) out[0] = wd * (1.0f / (float)NB);
}

extern "C" void kernel_launch(void* const* d_in, const int* in_sizes, int n_in,
                              void* d_out, int out_size, void* d_ws, size_t ws_size,
                              hipStream_t stream) {
    const float* pred = (const float*)d_in[0];
    const float* mask = (const float*)d_in[1];
    float* out  = (float*)d_out;
    float* part = (float*)d_ws;   // 2048 floats = 8 KB

    dim3 grid(NSTRIP, NB);        // 16 x 64 = 1024 blocks
    dice_fused_kernel<<<grid, 512, 0, stream>>>(pred, mask, part);
    dice_final_kernel<<<1, 64, 0, stream>>>(part, out);
}

// Round 5
// 150.178 us; speedup vs baseline: 1.2776x; 1.2776x over previous
//
#include <hip/hip_runtime.h>
#include <math.h>

#define NB 64
#define HH 512
#define WW 512
#define KK 31
#define PP 15
#define TS 32                 // output rows per strip
#define NSTRIP (HH / TS)      // 16 strips per image
#define HR (TS + KK - 1)      // 62 H rows held in LDS
#define NPAIR (HR / 2)        // 31 row pairs in phase 1

typedef _Float16 f16;
typedef f16 f16x8 __attribute__((ext_vector_type(8)));
typedef f16 f16x4 __attribute__((ext_vector_type(4)));
typedef f16 f16x2 __attribute__((ext_vector_type(2)));

__device__ __forceinline__ f16x2 shfl_up2(f16x2 v, int delta) {
    int x = __shfl_up(__builtin_bit_cast(int, v), delta);
    return __builtin_bit_cast(f16x2, x);
}
__device__ __forceinline__ f16x2 shfl_dn2(f16x2 v, int delta) {
    int x = __shfl_down(__builtin_bit_cast(int, v), delta);
    return __builtin_bit_cast(f16x2, x);
}
__device__ __forceinline__ f16x2 sel2(bool c, f16x2 v) {
    f16x2 z = {(f16)0, (f16)0};
    return c ? v : z;
}
// anchor: force a float4 to be materialized in VGPRs at this program point
__device__ __forceinline__ void keep4(float4& v) {
    asm volatile("" : "+v"(v.x), "+v"(v.y), "+v"(v.z), "+v"(v.w));
}

// ws layout: part[0..1023] = per-block inter, part[1024..2047] = per-block union

__global__ __launch_bounds__(512, 4) void dice_fused_kernel(
        const float* __restrict__ pred,
        const float* __restrict__ mask,
        float* __restrict__ part) {
    const int strip = blockIdx.x;
    const int b     = blockIdx.y;
    const int t     = threadIdx.x;
    const int wave  = t >> 6;
    const int lane  = t & 63;

    __shared__ f16 Hs[HR][WW];    // 62 x 512 fp16 = 63.5 KB : horizontal box sums
    __shared__ float red[16];     // total ~63.6 KB -> 2 blocks/CU

    const float* mb = mask + (size_t)b * HH * WW;
    const float* pb = pred + (size_t)b * HH * WW;
    const int y0 = strip * TS;

    // ============ Phase 1: H rows [y0-15, y0+46], local-tap method, 2 rows packed ==
    const int xbase = lane * 8;
    const bool lm1 = (lane >= 1);
    const bool lm2 = (lane >= 2);
    const bool lp1 = (lane <= 62);
    const bool lp2 = (lane <= 61);

    float va[4][8], vb[4][8];
    #pragma unroll
    for (int k = 0; k < 4; ++k) {
        const int p = k * 8 + wave;          // pair index 0..31 (31 invalid)
        const int gya = y0 + 2 * p - PP;
        const int gyb = gya + 1;
        const bool pa = (p < NPAIR) && (gya >= 0) && (gya < HH);
        const bool qb = (p < NPAIR) && (gyb >= 0) && (gyb < HH);
        if (pa) {
            const float* row = mb + (size_t)gya * WW + xbase;
            const float4 u = *(const float4*)(row);
            const float4 v = *(const float4*)(row + 4);
            va[k][0] = u.x; va[k][1] = u.y; va[k][2] = u.z; va[k][3] = u.w;
            va[k][4] = v.x; va[k][5] = v.y; va[k][6] = v.z; va[k][7] = v.w;
        } else {
            #pragma unroll
            for (int j = 0; j < 8; ++j) va[k][j] = 0.0f;
        }
        if (qb) {
            const float* row = mb + (size_t)gyb * WW + xbase;
            const float4 u = *(const float4*)(row);
            const float4 v = *(const float4*)(row + 4);
            vb[k][0] = u.x; vb[k][1] = u.y; vb[k][2] = u.z; vb[k][3] = u.w;
            vb[k][4] = v.x; vb[k][5] = v.y; vb[k][6] = v.z; vb[k][7] = v.w;
        } else {
            #pragma unroll
            for (int j = 0; j < 8; ++j) vb[k][j] = 0.0f;
        }
    }

    #pragma unroll
    for (int k = 0; k < 4; ++k) {
        const int p = k * 8 + wave;
        if (p >= NPAIR) continue;            // only wave 7, k=3 drops out
        const int ra = 2 * p;
        const int rb = ra + 1;

        float sa[8], sb[8];
        sa[0] = va[k][0]; sb[0] = vb[k][0];
        #pragma unroll
        for (int j = 1; j < 8; ++j) { sa[j] = sa[j-1] + va[k][j]; sb[j] = sb[j-1] + vb[k][j]; }

        f16x2 ps[8];
        #pragma unroll
        for (int j = 0; j < 8; ++j)
            ps[j] = __builtin_bit_cast(f16x2, __builtin_amdgcn_cvt_pkrtz(sa[j], sb[j]));
        const f16x2 pT = ps[7];

        f16x2 A[7];
        #pragma unroll
        for (int j = 0; j < 7; ++j) A[j] = shfl_up2(pT - ps[j], 2);
        const f16x2 Bprev = shfl_up2(pT, 1);
        const f16x2 Cfull = shfl_dn2(pT, 1);
        f16x2 Cp[7];
        #pragma unroll
        for (int j = 0; j < 7; ++j) Cp[j] = shfl_dn2(ps[j], 2);

        f16x2 base = pT;
        base += sel2(lm1, Bprev);
        base += sel2(lp1, Cfull);

        f16x8 ha, hb;
        #pragma unroll
        for (int j = 0; j < 8; ++j) {
            f16x2 acc = base;
            if (j < 7) acc += sel2(lm2, A[j]);
            if (j > 0) acc += sel2(lp2, Cp[j-1]);
            ha[j] = acc[0];
            hb[j] = acc[1];
        }
        *(f16x8*)&Hs[ra][xbase] = ha;
        *(f16x8*)&Hs[rb][xbase] = hb;
    }
    __syncthreads();

    // ================= Phase 2: vertical running 31-sum + fused epilogue ===========
    const int q  = t & 127;
    const int g  = t >> 7;               // 0..3
    const int c  = q * 4;
    const int r0 = g * 8;                // first output row (strip-relative)

    // Global loads issued HERE (after barrier), anchored so they can't be sunk
    // into the loop.  Liveness spans only the warm-up (~105 VGPR peak, no spill);
    // latency hides under the 45 LDS reads below.
    float4 M[8], Pq[8];
    #pragma unroll
    for (int i = 0; i < 8; ++i) {
        const int y = y0 + r0 + i;
        M[i]  = *(const float4*)(mb + (size_t)y * WW + c);
        Pq[i] = *(const float4*)(pb + (size_t)y * WW + c);
    }
    #pragma unroll
    for (int i = 0; i < 8; ++i) { keep4(M[i]); keep4(Pq[i]); }

    // Warm-up in packed fp16 (v_pk_add_f16), two 15-row partial sums for accuracy.
    // hl rows (r0..r0+7) saved during warm-up; he rows pre-read -> inner loop is
    // pure register math (numerics validated round 4: absmax 0.0).
    f16x4 hl8[8], he8[8];
    f16x4 accA = {(f16)0, (f16)0, (f16)0, (f16)0};
    f16x4 accB = {(f16)0, (f16)0, (f16)0, (f16)0};
    #pragma unroll
    for (int j = 0; j < 8; ++j) {            // rows r0..r0+7: save + accumulate
        hl8[j] = *(const f16x4*)&Hs[r0 + j][c];
        accA += hl8[j];
    }
    #pragma unroll
    for (int j = 8; j < 15; ++j) accA += *(const f16x4*)&Hs[r0 + j][c];
    #pragma unroll
    for (int j = 15; j < 30; ++j) accB += *(const f16x4*)&Hs[r0 + j][c];
    #pragma unroll
    for (int i = 0; i < 8; ++i) he8[i] = *(const f16x4*)&Hs[r0 + 30 + i][c];

    float4 B;
    B.x = (float)accA[0] + (float)accB[0];
    B.y = (float)accA[1] + (float)accB[1];
    B.z = (float)accA[2] + (float)accB[2];
    B.w = (float)accA[3] + (float)accB[3];

    float4 I4 = make_float4(0.f, 0.f, 0.f, 0.f);
    float4 U4 = make_float4(0.f, 0.f, 0.f, 0.f);
    const float inv2 = 1.0f / (float)(KK * KK);

    #pragma unroll
    for (int i = 0; i < 8; ++i) {
        const f16x4 he = he8[i];
        const f16x4 hl = hl8[i];
        const float4 m4 = M[i];
        const float4 p4 = Pq[i];

        B.x += (float)he[0]; B.y += (float)he[1]; B.z += (float)he[2]; B.w += (float)he[3];

        const float w0 = fmaf(5.0f, fabsf(fmaf(B.x, inv2, -m4.x)), 1.0f);
        const float w1 = fmaf(5.0f, fabsf(fmaf(B.y, inv2, -m4.y)), 1.0f);
        const float w2 = fmaf(5.0f, fabsf(fmaf(B.z, inv2, -m4.z)), 1.0f);
        const float w3 = fmaf(5.0f, fabsf(fmaf(B.w, inv2, -m4.w)), 1.0f);
        const float sg0 = __builtin_amdgcn_rcpf(1.0f + __expf(-p4.x));
        const float sg1 = __builtin_amdgcn_rcpf(1.0f + __expf(-p4.y));
        const float sg2 = __builtin_amdgcn_rcpf(1.0f + __expf(-p4.z));
        const float sg3 = __builtin_amdgcn_rcpf(1.0f + __expf(-p4.w));

        I4.x = fmaf(sg0 * m4.x, w0, I4.x);  U4.x = fmaf(sg0 + m4.x, w0, U4.x);
        I4.y = fmaf(sg1 * m4.y, w1, I4.y);  U4.y = fmaf(sg1 + m4.y, w1, U4.y);
        I4.z = fmaf(sg2 * m4.z, w2, I4.z);  U4.z = fmaf(sg2 + m4.z, w2, U4.z);
        I4.w = fmaf(sg3 * m4.w, w3, I4.w);  U4.w = fmaf(sg3 + m4.w, w3, U4.w);

        B.x -= (float)hl[0]; B.y -= (float)hl[1]; B.z -= (float)hl[2]; B.w -= (float)hl[3];
    }

    // ================= Block reduction -> per-block partials ======================
    float inter = I4.x + I4.y + I4.z + I4.w;
    float uni   = U4.x + U4.y + U4.z + U4.w;
    #pragma unroll
    for (int off = 32; off > 0; off >>= 1) {
        inter += __shfl_down(inter, off);
        uni   += __shfl_down(uni, off);
    }
    if (lane == 0) { red[wave] = inter; red[8 + wave] = uni; }
    __syncthreads();
    if (t == 0) {
        float ti = 0.f, tu = 0.f;
        #pragma unroll
        for (int w2 = 0; w2 < 8; ++w2) { ti += red[w2]; tu += red[8 + w2]; }
        const int bid = b * NSTRIP + strip;
        part[bid] = ti;
        part[NB * NSTRIP + bid] = tu;
    }
}

// ---------------- Final reduction ---------------
__global__ void dice_final_kernel(const float* __restrict__ part,
                                  float* __restrict__ out) {
    const int t = threadIdx.x;  // 64 threads, one per image
    float inter = 0.0f, uni = 0.0f;
    #pragma unroll
    for (int s = 0; s < NSTRIP; ++s) {
        inter += part[t * NSTRIP + s];
        uni   += part[NB * NSTRIP + t * NSTRIP + s];
    }
    float wd = 1.0f - (2.0f * inter + 0.5f) / (uni + 0.5f);
    #pragma unroll
    for (int off = 32; off > 0; off >>= 1) wd += __shfl_down(wd, off);
    if (t == 0) out[0] = wd * (1.0f / (float)NB);
}

extern "C" void kernel_launch(void* const* d_in, const int* in_sizes, int n_in,
                              void* d_out, int out_size, void* d_ws, size_t ws_size,
                              hipStream_t stream) {
    const float* pred = (const float*)d_in[0];
    const float* mask = (const float*)d_in[1];
    float* out  = (float*)d_out;
    float* part = (float*)d_ws;   // 2048 floats = 8 KB

    dim3 grid(NSTRIP, NB);        // 16 x 64 = 1024 blocks
    dice_fused_kernel<<<grid, 512, 0, stream>>>(pred, mask, part);
    dice_final_kernel<<<1, 64, 0, stream>>>(part, out);
}

// Round 6
// 146.379 us; speedup vs baseline: 1.3107x; 1.0259x over previous
//
#include <hip/hip_runtime.h>
#include <math.h>

#define NB 64
#define HH 512
#define WW 512
#define KK 31
#define PP 15
#define TSP 128               // output rows per block (4 x 32-row sub-strips)
#define NSP (HH / TSP)        // 4 row-bands per image -> grid 256 blocks = 1/CU
#define RING 64               // LDS ring rows (power of two >= 62-row window)
#define RMASK (RING - 1)

typedef _Float16 f16;
typedef f16 f16x8 __attribute__((ext_vector_type(8)));
typedef f16 f16x4 __attribute__((ext_vector_type(4)));
typedef f16 f16x2 __attribute__((ext_vector_type(2)));

__device__ __forceinline__ f16x2 shfl_up2(f16x2 v, int delta) {
    int x = __shfl_up(__builtin_bit_cast(int, v), delta);
    return __builtin_bit_cast(f16x2, x);
}
__device__ __forceinline__ f16x2 shfl_dn2(f16x2 v, int delta) {
    int x = __shfl_down(__builtin_bit_cast(int, v), delta);
    return __builtin_bit_cast(f16x2, x);
}
__device__ __forceinline__ f16x2 sel2(bool c, f16x2 v) {
    f16x2 z = {(f16)0, (f16)0};
    return c ? v : z;
}

// ---- Phase 1: horizontal 31-sum of mask rows (local-tap method, 2 rows packed).
// Writes H rows into the Hs ring (slot = h & 63) and stashes the raw center-band
// mask rows as fp16 into the Ms ring (slot = yr & 63) so phase 2 never re-reads
// mask from global (-64 MB VMEM).
template<int NK, bool CHECK>
__device__ __forceinline__ void phase1_pairs(
        const float* __restrict__ mb, f16 (* __restrict__ Hs)[WW],
        f16 (* __restrict__ Ms)[WW],
        const int y0, const int pfirst, const int wave, const int lane)
{
    const int xbase = lane * 8;
    const bool lm1 = (lane >= 1);
    const bool lm2 = (lane >= 2);
    const bool lp1 = (lane <= 62);
    const bool lp2 = (lane <= 61);

    #pragma unroll
    for (int k = 0; k < NK; ++k) {
        const int p = pfirst + k * 8 + wave;
        if (CHECK && p > 30) continue;        // init call: 31 pairs over 8 waves
        const int h0  = 2 * p;                // H row index (ring space is h&63)
        const int gy0 = y0 + h0 - PP;
        const int gy1 = gy0 + 1;

        float va[8], vb[8];
        if (gy0 >= 0 && gy0 < HH) {
            const float* row = mb + (size_t)gy0 * WW + xbase;
            const float4 u = *(const float4*)(row);
            const float4 v = *(const float4*)(row + 4);
            va[0] = u.x; va[1] = u.y; va[2] = u.z; va[3] = u.w;
            va[4] = v.x; va[5] = v.y; va[6] = v.z; va[7] = v.w;
        } else {
            #pragma unroll
            for (int j = 0; j < 8; ++j) va[j] = 0.0f;
        }
        if (gy1 >= 0 && gy1 < HH) {
            const float* row = mb + (size_t)gy1 * WW + xbase;
            const float4 u = *(const float4*)(row);
            const float4 v = *(const float4*)(row + 4);
            vb[0] = u.x; vb[1] = u.y; vb[2] = u.z; vb[3] = u.w;
            vb[4] = v.x; vb[5] = v.y; vb[6] = v.z; vb[7] = v.w;
        } else {
            #pragma unroll
            for (int j = 0; j < 8; ++j) vb[j] = 0.0f;
        }

        // stash raw center-band mask rows (yr in [0, TSP))
        const int yr0 = h0 - PP;              // gy0 - y0
        if (yr0 >= 0 && yr0 < TSP) {
            f16x8 mv;
            #pragma unroll
            for (int j = 0; j < 8; ++j) mv[j] = (f16)va[j];
            *(f16x8*)&Ms[yr0 & RMASK][xbase] = mv;
        }
        if (yr0 + 1 >= 0 && yr0 + 1 < TSP) {
            f16x8 mv;
            #pragma unroll
            for (int j = 0; j < 8; ++j) mv[j] = (f16)vb[j];
            *(f16x8*)&Ms[(yr0 + 1) & RMASK][xbase] = mv;
        }

        // in-lane inclusive prefixes (fp32)
        float sa[8], sb[8];
        sa[0] = va[0]; sb[0] = vb[0];
        #pragma unroll
        for (int j = 1; j < 8; ++j) { sa[j] = sa[j-1] + va[j]; sb[j] = sb[j-1] + vb[j]; }

        f16x2 ps[8];
        #pragma unroll
        for (int j = 0; j < 8; ++j)
            ps[j] = __builtin_bit_cast(f16x2, __builtin_amdgcn_cvt_pkrtz(sa[j], sb[j]));
        const f16x2 pT = ps[7];

        f16x2 A[7];
        #pragma unroll
        for (int j = 0; j < 7; ++j) A[j] = shfl_up2(pT - ps[j], 2);
        const f16x2 Bprev = shfl_up2(pT, 1);
        const f16x2 Cfull = shfl_dn2(pT, 1);
        f16x2 Cp[7];
        #pragma unroll
        for (int j = 0; j < 7; ++j) Cp[j] = shfl_dn2(ps[j], 2);

        f16x2 base = pT;
        base += sel2(lm1, Bprev);
        base += sel2(lp1, Cfull);

        f16x8 ha, hb;
        #pragma unroll
        for (int j = 0; j < 8; ++j) {
            f16x2 acc = base;
            if (j < 7) acc += sel2(lm2, A[j]);
            if (j > 0) acc += sel2(lp2, Cp[j-1]);
            ha[j] = acc[0];
            hb[j] = acc[1];
        }
        *(f16x8*)&Hs[h0 & RMASK][xbase] = ha;
        *(f16x8*)&Hs[(h0 + 1) & RMASK][xbase] = hb;
    }
}

// ---- Phase 2: one 32-row sub-strip (vertical running 31-sum + fused epilogue).
// mask comes from the fp16 LDS stash; only pred is read from global.
__device__ __forceinline__ void phase2_half(
        const float* __restrict__ pb,
        const f16 (* __restrict__ Hs)[WW], const f16 (* __restrict__ Ms)[WW],
        const int y0, const int r0h, const int c,
        float4& I4, float4& U4)
{
    f16x4 hl8[8], he8[8];
    f16x4 accA = {(f16)0, (f16)0, (f16)0, (f16)0};
    f16x4 accB = {(f16)0, (f16)0, (f16)0, (f16)0};
    #pragma unroll
    for (int j = 0; j < 8; ++j) {
        hl8[j] = *(const f16x4*)&Hs[(r0h + j) & RMASK][c];
        accA += hl8[j];
    }
    #pragma unroll
    for (int j = 8; j < 15; ++j) accA += *(const f16x4*)&Hs[(r0h + j) & RMASK][c];
    #pragma unroll
    for (int j = 15; j < 30; ++j) accB += *(const f16x4*)&Hs[(r0h + j) & RMASK][c];
    #pragma unroll
    for (int i = 0; i < 8; ++i) he8[i] = *(const f16x4*)&Hs[(r0h + 30 + i) & RMASK][c];

    float4 B;
    B.x = (float)accA[0] + (float)accB[0];
    B.y = (float)accA[1] + (float)accB[1];
    B.z = (float)accA[2] + (float)accB[2];
    B.w = (float)accA[3] + (float)accB[3];

    const float inv2 = 1.0f / (float)(KK * KK);

    #pragma unroll
    for (int i = 0; i < 8; ++i) {
        const int yr = r0h + i;
        const f16x4 he = he8[i];
        const f16x4 hl = hl8[i];
        const f16x4 mm = *(const f16x4*)&Ms[yr & RMASK][c];
        const float4 p4 = *(const float4*)(pb + (size_t)(y0 + yr) * WW + c);
        const float m0 = (float)mm[0], m1 = (float)mm[1];
        const float m2 = (float)mm[2], m3 = (float)mm[3];

        B.x += (float)he[0]; B.y += (float)he[1]; B.z += (float)he[2]; B.w += (float)he[3];

        const float w0 = fmaf(5.0f, fabsf(fmaf(B.x, inv2, -m0)), 1.0f);
        const float w1 = fmaf(5.0f, fabsf(fmaf(B.y, inv2, -m1)), 1.0f);
        const float w2 = fmaf(5.0f, fabsf(fmaf(B.z, inv2, -m2)), 1.0f);
        const float w3 = fmaf(5.0f, fabsf(fmaf(B.w, inv2, -m3)), 1.0f);
        const float sg0 = __builtin_amdgcn_rcpf(1.0f + __expf(-p4.x));
        const float sg1 = __builtin_amdgcn_rcpf(1.0f + __expf(-p4.y));
        const float sg2 = __builtin_amdgcn_rcpf(1.0f + __expf(-p4.z));
        const float sg3 = __builtin_amdgcn_rcpf(1.0f + __expf(-p4.w));

        I4.x = fmaf(sg0 * m0, w0, I4.x);  U4.x = fmaf(sg0 + m0, w0, U4.x);
        I4.y = fmaf(sg1 * m1, w1, I4.y);  U4.y = fmaf(sg1 + m1, w1, U4.y);
        I4.z = fmaf(sg2 * m2, w2, I4.z);  U4.z = fmaf(sg2 + m2, w2, U4.z);
        I4.w = fmaf(sg3 * m3, w3, I4.w);  U4.w = fmaf(sg3 + m3, w3, U4.w);

        B.x -= (float)hl[0]; B.y -= (float)hl[1]; B.z -= (float)hl[2]; B.w -= (float)hl[3];
    }
}

// ws layout: part[0..255] = per-block inter, part[256..511] = per-block union

__global__ __launch_bounds__(512, 2) void dice_fused_kernel(
        const float* __restrict__ pred,
        const float* __restrict__ mask,
        float* __restrict__ part) {
    const int sp = blockIdx.x;           // 0..3 row-band
    const int b  = blockIdx.y;
    const int t  = threadIdx.x;
    const int wave = t >> 6;
    const int lane = t & 63;

    __shared__ f16 Hs[RING][WW];         // 64 KB: horizontal-box-sum ring
    __shared__ f16 Ms[RING][WW];         // 64 KB: fp16 mask stash ring
    __shared__ float red[16];            // ~128.1 KB total -> 1 block/CU

    const float* mb = mask + (size_t)b * HH * WW;
    const float* pb = pred + (size_t)b * HH * WW;
    const int y0 = sp * TSP;

    // initial fill: H rows h=0..61 (pairs 0..30)
    phase1_pairs<4, true>(mb, Hs, Ms, y0, 0, wave, lane);
    __syncthreads();

    const int q = t & 127;
    const int g = t >> 7;                // 0..3
    const int c = q * 4;

    float4 I4 = make_float4(0.f, 0.f, 0.f, 0.f);
    float4 U4 = make_float4(0.f, 0.f, 0.f, 0.f);

    #pragma unroll
    for (int half = 0; half < 4; ++half) {
        phase2_half(pb, Hs, Ms, y0, g * 8 + 32 * half, c, I4, U4);
        __syncthreads();                 // readers done before ring overwrite
        if (half < 3) {
            // next 32 H rows: pairs 31+16*half .. 46+16*half (16 pairs, 2 k-iters)
            phase1_pairs<2, false>(mb, Hs, Ms, y0, 31 + 16 * half, wave, lane);
            __syncthreads();
        }
    }

    // ================= Block reduction -> per-block partials ======================
    float inter = I4.x + I4.y + I4.z + I4.w;
    float uni   = U4.x + U4.y + U4.z + U4.w;
    #pragma unroll
    for (int off = 32; off > 0; off >>= 1) {
        inter += __shfl_down(inter, off);
        uni   += __shfl_down(uni, off);
    }
    if (lane == 0) { red[wave] = inter; red[8 + wave] = uni; }
    __syncthreads();
    if (t == 0) {
        float ti = 0.f, tu = 0.f;
        #pragma unroll
        for (int w2 = 0; w2 < 8; ++w2) { ti += red[w2]; tu += red[8 + w2]; }
        const int bid = b * NSP + sp;
        part[bid] = ti;
        part[NB * NSP + bid] = tu;
    }
}

// ---------------- Final reduction ---------------
__global__ void dice_final_kernel(const float* __restrict__ part,
                                  float* __restrict__ out) {
    const int t = threadIdx.x;  // 64 threads, one per image
    float inter = 0.0f, uni = 0.0f;
    #pragma unroll
    for (int s = 0; s < NSP; ++s) {
        inter += part[t * NSP + s];
        uni   += part[NB * NSP + t * NSP + s];
    }
    float wd = 1.0f - (2.0f * inter + 0.5f) / (uni + 0.5f);
    #pragma unroll
    for (int off = 32; off > 0; off >>= 1) wd += __shfl_down(wd, off);
    if (t == 0) out[0] = wd * (1.0f / (float)NB);
}

extern "C" void kernel_launch(void* const* d_in, const int* in_sizes, int n_in,
                              void* d_out, int out_size, void* d_ws, size_t ws_size,
                              hipStream_t stream) {
    const float* pred = (const float*)d_in[0];
    const float* mask = (const float*)d_in[1];
    float* out  = (float*)d_out;
    float* part = (float*)d_ws;   // 512 floats = 2 KB

    dim3 grid(NSP, NB);           // 4 x 64 = 256 blocks = exactly 1 per CU
    dice_fused_kernel<<<grid, 512, 0, stream>>>(pred, mask, part);
    dice_final_kernel<<<1, 64, 0, stream>>>(part, out);
}